// Round 4
// baseline (56.535 us; speedup 1.0000x reference)
//
#include <hip/hip_runtime.h>
#include <hip/hip_bf16.h>

#define NROWS 8192
#define DIM   128
#define TOTAL_OUT 33550336u       // NROWS*(NROWS-1)/2
// tiles: 256 rows (l) x 64 rows (u); bj in [0,128), bi in [0, bj/4]
#define NBLK2 2112                // sum over bj of (bj/4 + 1)

typedef short bf16x8 __attribute__((ext_vector_type(8)));
typedef float f32x4  __attribute__((ext_vector_type(4)));
typedef unsigned short u16x8 __attribute__((ext_vector_type(8)));

// fp32 -> bf16 round-to-nearest-even
static __device__ inline unsigned short f32_to_bf16(float f) {
    unsigned int u = __float_as_uint(f);
    u += 0x7FFFu + ((u >> 16) & 1u);
    return (unsigned short)(u >> 16);
}

// cumulative tile count before column bj: C(bj) = 2q(q+1) + r(q+1), q=bj>>2, r=bj&3
static __device__ inline int cumtiles(int b) {
    int q = b >> 2, r = b & 3;
    return 2 * q * (q + 1) + r * (q + 1);
}

// Block = one 16-row group. bf16 convert + FRAGMENT-MAJOR layout:
//   Xr[((g*4 + kk)*64 + lane)*8] : row g*16+(lane&15), cols ((kk*4+(lane>>4))*8 ..+8)
// Each MFMA fragment load in pdist = one contiguous 1KB wave load. Also fp32 norms.
__global__ __launch_bounds__(256) void prep_kernel(const float* __restrict__ X,
                                                   unsigned short* __restrict__ Xr,
                                                   float* __restrict__ sq,
                                                   float* __restrict__ out) {
    __shared__ float sm[16][17];
    const int g = blockIdx.x;
    const int t = threadIdx.x;
    const int kk = t >> 6, lane = t & 63;
    const int lrow = lane & 15, kgrp = lane >> 4;

    const float* src = X + (size_t)(g * 16 + lrow) * DIM + (kk * 4 + kgrp) * 8;
    const float4 v0 = *reinterpret_cast<const float4*>(src);
    const float4 v1 = *reinterpret_cast<const float4*>(src + 4);

    u16x8 h;
    h[0] = f32_to_bf16(v0.x); h[1] = f32_to_bf16(v0.y);
    h[2] = f32_to_bf16(v0.z); h[3] = f32_to_bf16(v0.w);
    h[4] = f32_to_bf16(v1.x); h[5] = f32_to_bf16(v1.y);
    h[6] = f32_to_bf16(v1.z); h[7] = f32_to_bf16(v1.w);
    *reinterpret_cast<u16x8*>(Xr + ((size_t)(g * 4 + kk) * 64 + lane) * 8) = h;

    float p = v0.x * v0.x + v0.y * v0.y + v0.z * v0.z + v0.w * v0.w
            + v1.x * v1.x + v1.y * v1.y + v1.z * v1.z + v1.w * v1.w;
    sm[lrow][kk * 4 + kgrp] = p;
    __syncthreads();
    if (t < 16) {
        float s = 0.f;
        #pragma unroll
        for (int j = 0; j < 16; ++j) s += sm[t][j];
        sq[g * 16 + t] = s;
    }
    if (g == 0 && t == 0) out[TOTAL_OUT - 1] = 0.0f; // skipped pair (0,1) slot
}

// 256(l) x 64(u) tile per block, 4 waves = 4 l-strips of 64. No staging LDS
// (input is L2-resident, fragment-major). Epilogue: dist into 32KB LDS with
// XOR chunk swizzle, read back u-major, store FULL 1KB contiguous runs per
// u-row so L2 write misses are full-line (no read-allocate from HBM).
__global__ __launch_bounds__(256, 4) void pdist_kernel(const unsigned short* __restrict__ Xr,
                                                       const float* __restrict__ sq,
                                                       float* __restrict__ out) {
    __shared__ f32x4 smC[32 * 64];   // 32 u-rows x 64 chunks(16B) = 32KB per pass

    const int t  = threadIdx.x;
    const int bt = blockIdx.x;
    int bj = (int)sqrtf(8.0f * (float)bt + 1.0f);
    if (bj > 127) bj = 127;
    while (cumtiles(bj) > bt) --bj;
    while (bj < 127 && cumtiles(bj + 1) <= bt) ++bj;
    const int bi = bt - cumtiles(bj);   // l-tile, 0..bj/4

    const int wid  = t >> 6;
    const int lane = t & 63;
    const int wr   = wid;        // wave = one 64-row l strip
    const int lrow = lane & 15;
    const int kgrp = lane >> 4;

    const bf16x8* __restrict__ F = reinterpret_cast<const bf16x8*>(Xr);
    const int gA = bi * 16 + wr * 4;  // 16-row group base for A (+m)
    const int gB = bj * 4;            // 16-row group base for B (+n), shared by all waves

    f32x4 acc[4][4];
    const f32x4 fzero = {0.f, 0.f, 0.f, 0.f};
    #pragma unroll
    for (int m = 0; m < 4; ++m)
        #pragma unroll
        for (int n = 0; n < 4; ++n) acc[m][n] = fzero;

    bf16x8 a[2][4], b[2][4];
    #pragma unroll
    for (int m = 0; m < 4; ++m) {
        a[0][m] = F[((gA + m) * 4 + 0) * 64 + lane];
        b[0][m] = F[((gB + m) * 4 + 0) * 64 + lane];
    }
    #pragma unroll
    for (int kk = 0; kk < 4; ++kk) {
        const int cur = kk & 1, nxt = cur ^ 1;
        if (kk < 3) {
            #pragma unroll
            for (int m = 0; m < 4; ++m) {
                a[nxt][m] = F[((gA + m) * 4 + kk + 1) * 64 + lane];
                b[nxt][m] = F[((gB + m) * 4 + kk + 1) * 64 + lane];
            }
        }
        #pragma unroll
        for (int m = 0; m < 4; ++m)
            #pragma unroll
            for (int n = 0; n < 4; ++n)
                acc[m][n] = __builtin_amdgcn_mfma_f32_16x16x32_bf16(a[cur][m], b[cur][n], acc[m][n], 0, 0, 0);
    }

    // ---- epilogue ----
    const int u0  = bj * 64;
    const int l0w = bi * 256 + wr * 64;          // wave's l base
    const bool diag = (bi == (bj >> 2));         // tile crosses the diagonal

    float squ[4];
    f32x4 sql[4];
    #pragma unroll
    for (int n = 0; n < 4; ++n) squ[n] = sq[u0 + n * 16 + lrow];
    #pragma unroll
    for (int m = 0; m < 4; ++m)
        sql[m] = *reinterpret_cast<const f32x4*>(sq + l0w + m * 16 + kgrp * 4);

    #pragma unroll
    for (int h = 0; h < 2; ++h) {                // two 32-u-row passes
        if (h) __syncthreads();                  // protect LDS reuse
        // write: dist values, chunk c = l/4 within 256-l row, slot = c ^ (u&15)
        #pragma unroll
        for (int m = 0; m < 4; ++m) {
            #pragma unroll
            for (int nn = 0; nn < 2; ++nn) {
                const int n = 2 * h + nn;
                const int u_loc = nn * 16 + lrow;        // 0..31, (u_loc&15)==lrow
                const int c = wr * 16 + m * 4 + kgrp;
                f32x4 d;
                #pragma unroll
                for (int j = 0; j < 4; ++j) d[j] = sql[m][j] + squ[n] - 2.0f * acc[m][n][j];
                smC[u_loc * 64 + (c ^ lrow)] = d;
            }
        }
        __syncthreads();
        // read + store: one full u-row (1KB contiguous) per wave-instruction
        #pragma unroll
        for (int r8 = 0; r8 < 8; ++r8) {
            const int u_loc = wid * 8 + r8;
            const int u = u0 + 32 * h + u_loc;
            const f32x4 v = smC[u_loc * 64 + (lane ^ (u_loc & 15))];
            const size_t base = (size_t)u * (u - 1) / 2 - 1 + (size_t)bi * 256;
            const int ll = lane * 4;
            if (!diag) {
                __builtin_memcpy(out + base + ll, &v, 16);
            } else if (u >= 2) {
                const int nvalid = u - bi * 256;         // valid l count in this tile
                if (ll + 3 < nvalid) {
                    __builtin_memcpy(out + base + ll, &v, 16);
                } else {
                    #pragma unroll
                    for (int j = 0; j < 4; ++j)
                        if (ll + j < nvalid) out[base + ll + j] = v[j];
                }
            }
        }
    }
}

extern "C" void kernel_launch(void* const* d_in, const int* in_sizes, int n_in,
                              void* d_out, int out_size, void* d_ws, size_t ws_size,
                              hipStream_t stream) {
    const float* X = (const float*)d_in[0];
    float* out = (float*)d_out;
    unsigned short* Xr = (unsigned short*)d_ws;                       // 2 MB bf16, fragment-major
    float* sq = (float*)((char*)d_ws + (size_t)NROWS * DIM * 2);      // 32 KB norms

    prep_kernel<<<NROWS / 16, 256, 0, stream>>>(X, Xr, sq, out);
    pdist_kernel<<<NBLK2, 256, 0, stream>>>(Xr, sq, out);
}